// Round 5
// baseline (189.716 us; speedup 1.0000x reference)
//
#include <hip/hip_runtime.h>
#include <math.h>

#define DEV __device__ __forceinline__

struct C2 { float x, y; };
DEV C2 cmul(C2 a, C2 b){ return {a.x*b.x - a.y*b.y, a.x*b.y + a.y*b.x}; }
DEV C2 cadd(C2 a, C2 b){ return {a.x+b.x, a.y+b.y}; }
DEV C2 cscale(C2 a, float s){ return {a.x*s, a.y*s}; }
DEV C2 cnegi(C2 a){ return {a.y, -a.x}; } // multiply by -i

// ---------------------------------------------------------------------------
// K1 (UNCHANGED from round 3 - verified): per block (c,b) -> rows
// r = b*2048 + c*32 + j. 512 threads = 8 waves = 4 wave-PAIRS. Pair pr owns
// rows pr*8..pr*8+7; wave half h covers K-range e in [h*256, h*256+256).
// Per-lane Wk slice is 4x4 float4 = 64 regs -> fits 4 waves/SIMD, no spill.
// ---------------------------------------------------------------------------
__global__ __launch_bounds__(512, 4) void k_score_wsum(const float* __restrict__ key,
                                                       const float* __restrict__ Wk,
                                                       const float* __restrict__ bk,
                                                       const float* __restrict__ value,
                                                       float* __restrict__ partial,
                                                       float* __restrict__ partialw)
{
    const int c = blockIdx.x;        // 0..63
    const int b = blockIdx.y;        // 0..7
    const int t = threadIdx.x;
    const int lane = t & 63;
    const int wv   = t >> 6;         // wave 0..7
    const int h    = wv & 1;         // K-half
    const int pr   = wv >> 1;        // pair 0..3
    const int base = b * 2048 + c * 32;
    const int wrow0 = pr * 8;        // pair's first row within chunk

    __shared__ float  kslds[2][32][16]; // half-k_states staging (4 KB)
    __shared__ float4 red[8][128];      // cross-wave column reduce (16 KB)
    __shared__ float  wsums[4];

    // per-lane Wk slice: rows h*256+4l..+3, all 16 cols (64 regs)
    float4 wk[4][4];
    #pragma unroll
    for (int jj = 0; jj < 4; ++jj) {
        const float4* w0 = (const float4*)(Wk + (h * 256 + 4 * lane + jj) * 16);
        #pragma unroll
        for (int q = 0; q < 4; ++q) wk[jj][q] = w0[q];
    }
    const float c0 = 0.30901699437494745f;   // cos(pi*0.8/2)
    const float s0 = 0.9510565162951535f;    // sin(pi*0.8/2)

    // ---- Phase A1: half-K k_states for the pair's 8 rows ----
    const float4* kp = (const float4*)(key + (size_t)(base + wrow0) * 512);
    float4 cur = kp[h * 64 + lane];
    #pragma unroll
    for (int j = 0; j < 8; ++j) {
        float4 nx;
        if (j < 7) nx = kp[(j + 1) * 128 + h * 64 + lane];
        float el[4] = {cur.x, cur.y, cur.z, cur.w};
        float acc[16];
        #pragma unroll
        for (int k = 0; k < 16; ++k) acc[k] = 0.f;
        #pragma unroll
        for (int jj = 0; jj < 4; ++jj) {
            #pragma unroll
            for (int q = 0; q < 4; ++q) {
                acc[4*q+0] = fmaf(el[jj], wk[jj][q].x, acc[4*q+0]);
                acc[4*q+1] = fmaf(el[jj], wk[jj][q].y, acc[4*q+1]);
                acc[4*q+2] = fmaf(el[jj], wk[jj][q].z, acc[4*q+2]);
                acc[4*q+3] = fmaf(el[jj], wk[jj][q].w, acc[4*q+3]);
            }
        }
        // butterfly: 4 stages -> acc[0] holds col (lane&15) partial for the
        // 16-lane group; then fold the 4 groups.
        #pragma unroll
        for (int s = 0; s < 4; ++s) {
            const int m = 1 << s;
            const int bbit = (lane >> s) & 1;
            #pragma unroll
            for (int jj = 0; jj < (16 >> (s + 1)); ++jj) {
                float send = bbit ? acc[2*jj] : acc[2*jj+1];
                float keep = bbit ? acc[2*jj+1] : acc[2*jj];
                acc[jj] = keep + __shfl_xor(send, m);
            }
        }
        float ks = acc[0];
        ks += __shfl_xor(ks, 16);
        ks += __shfl_xor(ks, 32);
        if (lane < 16) kslds[h][wrow0 + j][lane] = ks;
        cur = nx;
    }

    // ---- value prefetch: wave's 4 rows (issued before barrier) ----
    const int vrow0 = wrow0 + h * 4;            // rows vrow0..vrow0+3
    const float4* vp = (const float4*)(value + (size_t)(base + vrow0) * 512);
    float4 vreg[8];
    #pragma unroll
    for (int j = 0; j < 4; ++j) {
        vreg[2*j]   = vp[j * 128 + lane];
        vreg[2*j+1] = vp[j * 128 + 64 + lane];
    }
    __syncthreads();                 // kslds complete (both halves)

    // ---- Phase A2: scores for the pair's 8 rows (both waves redundant) ----
    const int p  = (lane >> 3) & 3;   // qubit-pair 0..3
    const int jr = lane & 7;          // row-in-pair 0..7
    float4 k0 = *(const float4*)&kslds[0][wrow0 + jr][4 * p];
    float4 k1 = *(const float4*)&kslds[1][wrow0 + jr][4 * p];
    float4 bk4 = ((const float4*)bk)[p];
    float ax = k0.x + k1.x + bk4.x, az = k0.y + k1.y + bk4.y;
    float bx = k0.z + k1.z + bk4.z, bz = k0.w + k1.w + bk4.w;
    float cxa = 1.f, sxa = 0.f; if (ax > 0.f){ sxa = __sinf(0.5f*ax); cxa = __cosf(0.5f*ax); }
    float cpa = 1.f, spa = 0.f; if (az > 0.f){ spa = __sinf(0.5f*az); cpa = __cosf(0.5f*az); }
    float cxb = 1.f, sxb = 0.f; if (bx > 0.f){ sxb = __sinf(0.5f*bx); cxb = __cosf(0.5f*bx); }
    float cpb = 1.f, spb = 0.f; if (bz > 0.f){ spb = __sinf(0.5f*bz); cpb = __cosf(0.5f*bz); }
    C2 A00{cpa*cxa, -spa*cxa}, A01{-spa*sxa, -cpa*sxa};
    C2 A10{spa*sxa, -cpa*sxa}, A11{ cpa*cxa,  spa*cxa};
    C2 B00{cpb*cxb, -spb*cxb}, B01{-spb*sxb, -cpb*sxb};
    C2 B10{spb*sxb, -cpb*sxb}, B11{ cpb*cxb,  spb*cxb};
    C2 u = cadd(cmul(B00, cadd(A00, cscale(A01, c0))),
                cscale(cnegi(cmul(A01, B01)), s0));
    C2 v = cadd(cmul(B10, cadd(A10, cscale(A11, c0))),
                cscale(cnegi(cmul(A11, B11)), s0));
    float ps = u.x*u.x + u.y*u.y + v.x*v.x + v.y*v.y;
    ps += __shfl_xor(ps, 8);          // fold qubit-pairs (p bits at 3..4)
    ps += __shfl_xor(ps, 16);
    float w_all = __expf(ps * 0.125f); // lane holds w for row (lane&7)

    // pair w-sum (h==0 wave writes; fold over row bits 0..2)
    if (h == 0) {
        float sw = w_all;
        sw += __shfl_xor(sw, 1); sw += __shfl_xor(sw, 2); sw += __shfl_xor(sw, 4);
        if (lane == 0) wsums[pr] = sw;
    }

    // ---- Phase B: weighted sum of own 4 value rows (from registers) ----
    float4 aA = {0.f,0.f,0.f,0.f}, aB = {0.f,0.f,0.f,0.f};
    #pragma unroll
    for (int j = 0; j < 4; ++j) {
        float wj = __shfl(w_all, h * 4 + j);
        float4 v0 = vreg[2*j], v1 = vreg[2*j+1];
        aA.x = fmaf(wj, v0.x, aA.x); aA.y = fmaf(wj, v0.y, aA.y);
        aA.z = fmaf(wj, v0.z, aA.z); aA.w = fmaf(wj, v0.w, aA.w);
        aB.x = fmaf(wj, v1.x, aB.x); aB.y = fmaf(wj, v1.y, aB.y);
        aB.z = fmaf(wj, v1.z, aB.z); aB.w = fmaf(wj, v1.w, aB.w);
    }
    red[wv][lane] = aA;
    red[wv][64 + lane] = aB;
    __syncthreads();
    if (t < 128) {
        float4 q0 = red[0][t], q1 = red[1][t], q2 = red[2][t], q3 = red[3][t];
        float4 q4 = red[4][t], q5 = red[5][t], q6 = red[6][t], q7 = red[7][t];
        float4 o = { q0.x+q1.x+q2.x+q3.x+q4.x+q5.x+q6.x+q7.x,
                     q0.y+q1.y+q2.y+q3.y+q4.y+q5.y+q6.y+q7.y,
                     q0.z+q1.z+q2.z+q3.z+q4.z+q5.z+q6.z+q7.z,
                     q0.w+q1.w+q2.w+q3.w+q4.w+q5.w+q6.w+q7.w };
        ((float4*)partial)[((size_t)b * 64 + c) * 128 + t] = o;
    }
    if (t == 0)
        partialw[b * 64 + c] = wsums[0] + wsums[1] + wsums[2] + wsums[3];
}

// ---------------------------------------------------------------------------
// K2 (tail, fuses old k_ctx + k_frow + k_bcast): grid (slice 0..7, b 0..7).
// Each block REDUNDANTLY (8x per batch) computes:
//   invS = 1/sum(partialw[b,:]);
//   cbuf = column sums of partial over 64 chunks;
//   xbuf = ctx = (cbuf*invS) @ Wv + bv        (512x512 GEMV, LDS x);
//   fr   = ctx @ Wo + bo                       (512x512 GEMV);
// then broadcast-writes fr to its 256 output rows (float4 stores).
// Redundancy cost ~2 us/block; Wv+Wo (2 MB) are L2-resident per XCD.
// Removes 2 dispatch gaps + ctx/frow global round-trips vs round 3.
// ---------------------------------------------------------------------------
__global__ __launch_bounds__(512) void k_tail(const float* __restrict__ partial,
                                              const float* __restrict__ partialw,
                                              const float* __restrict__ Wv,
                                              const float* __restrict__ bv,
                                              const float* __restrict__ Wo,
                                              const float* __restrict__ bo,
                                              float* __restrict__ out)
{
    const int sl = blockIdx.x;       // output slice 0..7 (256 rows each)
    const int b  = blockIdx.y;       // batch 0..7
    const int t  = threadIdx.x;      // 0..511

    __shared__ float cbuf[512];
    __shared__ float xbuf[512];
    __shared__ float frl[512];
    __shared__ float sS;

    // invS (wave 0)
    if (t < 64) {
        float s = partialw[b * 64 + t];
        s += __shfl_xor(s, 1);  s += __shfl_xor(s, 2);
        s += __shfl_xor(s, 4);  s += __shfl_xor(s, 8);
        s += __shfl_xor(s, 16); s += __shfl_xor(s, 32);
        if (t == 0) sS = 1.f / s;
    }

    // column sums over 64 chunks (coalesced; stride 512 floats)
    {
        float cs = 0.f;
        const float* pp = partial + (size_t)b * 32768 + t;
        #pragma unroll 8
        for (int cc = 0; cc < 64; ++cc) cs += pp[(size_t)cc * 512];
        cbuf[t] = cs;
    }
    __syncthreads();                 // cbuf + sS visible
    const float invS = sS;

    // ctx[t] = invS * sum_e cbuf[e]*Wv[e][t] + bv[t]
    {
        float a0 = 0.f, a1 = 0.f, a2 = 0.f, a3 = 0.f;
        #pragma unroll 4
        for (int e = 0; e < 512; e += 4) {
            a0 = fmaf(cbuf[e],   Wv[(size_t)e * 512 + t],     a0);
            a1 = fmaf(cbuf[e+1], Wv[(size_t)(e+1) * 512 + t], a1);
            a2 = fmaf(cbuf[e+2], Wv[(size_t)(e+2) * 512 + t], a2);
            a3 = fmaf(cbuf[e+3], Wv[(size_t)(e+3) * 512 + t], a3);
        }
        xbuf[t] = ((a0 + a1) + (a2 + a3)) * invS + bv[t];
    }
    __syncthreads();                 // ctx visible

    // fr[t] = sum_e ctx[e]*Wo[e][t] + bo[t]
    {
        float a0 = 0.f, a1 = 0.f, a2 = 0.f, a3 = 0.f;
        #pragma unroll 4
        for (int e = 0; e < 512; e += 4) {
            a0 = fmaf(xbuf[e],   Wo[(size_t)e * 512 + t],     a0);
            a1 = fmaf(xbuf[e+1], Wo[(size_t)(e+1) * 512 + t], a1);
            a2 = fmaf(xbuf[e+2], Wo[(size_t)(e+2) * 512 + t], a2);
            a3 = fmaf(xbuf[e+3], Wo[(size_t)(e+3) * 512 + t], a3);
        }
        frl[t] = ((a0 + a1) + (a2 + a3)) + bo[t];
    }
    __syncthreads();                 // frl visible

    // broadcast frl to rows [b*2048 + sl*256, +256), float4 stores.
    // thread -> (row-group rg = t>>7 of 64 rows, float4-col col4 = t&127)
    {
        const int col4 = t & 127, rg = t >> 7;
        float4 val = ((const float4*)frl)[col4];
        float4* o4 = (float4*)out
                   + ((size_t)b * 2048 + sl * 256 + rg * 64) * 128 + col4;
        #pragma unroll 8
        for (int r = 0; r < 64; ++r) o4[(size_t)r * 128] = val;
    }
}

extern "C" void kernel_launch(void* const* d_in, const int* in_sizes, int n_in,
                              void* d_out, int out_size, void* d_ws, size_t ws_size,
                              hipStream_t stream) {
    // setup_inputs order: query, key, value, Wq, bq, Wk, bk, Wv, bv, Wo, bo
    const float* key   = (const float*)d_in[1];
    const float* value = (const float*)d_in[2];
    const float* Wk    = (const float*)d_in[5];
    const float* bk    = (const float*)d_in[6];
    const float* Wv    = (const float*)d_in[7];
    const float* bv    = (const float*)d_in[8];
    const float* Wo    = (const float*)d_in[9];
    const float* bo    = (const float*)d_in[10];
    float* out = (float*)d_out;
    float* ws  = (float*)d_ws;

    // workspace layout (floats), ~1.05 MB
    float* partial  = ws;                 // 8*64*512 = 262144
    float* partialw = ws + 262144;        // 512

    k_score_wsum<<<dim3(64, 8), 512, 0, stream>>>(key, Wk, bk, value,
                                                  partial, partialw);
    k_tail      <<<dim3(8, 8),  512, 0, stream>>>(partial, partialw,
                                                  Wv, bv, Wo, bo, out);
}

// Round 6
// 168.814 us; speedup vs baseline: 1.1238x; 1.1238x over previous
//
#include <hip/hip_runtime.h>
#include <math.h>

#define DEV __device__ __forceinline__

struct C2 { float x, y; };
DEV C2 cmul(C2 a, C2 b){ return {a.x*b.x - a.y*b.y, a.x*b.y + a.y*b.x}; }
DEV C2 cadd(C2 a, C2 b){ return {a.x+b.x, a.y+b.y}; }
DEV C2 cscale(C2 a, float s){ return {a.x*s, a.y*s}; }
DEV C2 cnegi(C2 a){ return {a.y, -a.x}; } // multiply by -i

// ---------------------------------------------------------------------------
// K1 (UNCHANGED from round 3 - verified): per block (c,b) -> rows
// r = b*2048 + c*32 + j. 512 threads = 8 waves = 4 wave-PAIRS. Pair pr owns
// rows pr*8..pr*8+7; wave half h covers K-range e in [h*256, h*256+256).
// Per-lane Wk slice is 4x4 float4 = 64 regs -> fits 4 waves/SIMD, no spill.
// ---------------------------------------------------------------------------
__global__ __launch_bounds__(512, 4) void k_score_wsum(const float* __restrict__ key,
                                                       const float* __restrict__ Wk,
                                                       const float* __restrict__ bk,
                                                       const float* __restrict__ value,
                                                       float* __restrict__ partial,
                                                       float* __restrict__ partialw)
{
    const int c = blockIdx.x;        // 0..63
    const int b = blockIdx.y;        // 0..7
    const int t = threadIdx.x;
    const int lane = t & 63;
    const int wv   = t >> 6;         // wave 0..7
    const int h    = wv & 1;         // K-half
    const int pr   = wv >> 1;        // pair 0..3
    const int base = b * 2048 + c * 32;
    const int wrow0 = pr * 8;        // pair's first row within chunk

    __shared__ float  kslds[2][32][16]; // half-k_states staging (4 KB)
    __shared__ float4 red[8][128];      // cross-wave column reduce (16 KB)
    __shared__ float  wsums[4];

    // per-lane Wk slice: rows h*256+4l..+3, all 16 cols (64 regs)
    float4 wk[4][4];
    #pragma unroll
    for (int jj = 0; jj < 4; ++jj) {
        const float4* w0 = (const float4*)(Wk + (h * 256 + 4 * lane + jj) * 16);
        #pragma unroll
        for (int q = 0; q < 4; ++q) wk[jj][q] = w0[q];
    }
    const float c0 = 0.30901699437494745f;   // cos(pi*0.8/2)
    const float s0 = 0.9510565162951535f;    // sin(pi*0.8/2)

    // ---- Phase A1: half-K k_states for the pair's 8 rows ----
    const float4* kp = (const float4*)(key + (size_t)(base + wrow0) * 512);
    float4 cur = kp[h * 64 + lane];
    #pragma unroll
    for (int j = 0; j < 8; ++j) {
        float4 nx;
        if (j < 7) nx = kp[(j + 1) * 128 + h * 64 + lane];
        float el[4] = {cur.x, cur.y, cur.z, cur.w};
        float acc[16];
        #pragma unroll
        for (int k = 0; k < 16; ++k) acc[k] = 0.f;
        #pragma unroll
        for (int jj = 0; jj < 4; ++jj) {
            #pragma unroll
            for (int q = 0; q < 4; ++q) {
                acc[4*q+0] = fmaf(el[jj], wk[jj][q].x, acc[4*q+0]);
                acc[4*q+1] = fmaf(el[jj], wk[jj][q].y, acc[4*q+1]);
                acc[4*q+2] = fmaf(el[jj], wk[jj][q].z, acc[4*q+2]);
                acc[4*q+3] = fmaf(el[jj], wk[jj][q].w, acc[4*q+3]);
            }
        }
        // butterfly: 4 stages -> acc[0] holds col (lane&15) partial for the
        // 16-lane group; then fold the 4 groups.
        #pragma unroll
        for (int s = 0; s < 4; ++s) {
            const int m = 1 << s;
            const int bbit = (lane >> s) & 1;
            #pragma unroll
            for (int jj = 0; jj < (16 >> (s + 1)); ++jj) {
                float send = bbit ? acc[2*jj] : acc[2*jj+1];
                float keep = bbit ? acc[2*jj+1] : acc[2*jj];
                acc[jj] = keep + __shfl_xor(send, m);
            }
        }
        float ks = acc[0];
        ks += __shfl_xor(ks, 16);
        ks += __shfl_xor(ks, 32);
        if (lane < 16) kslds[h][wrow0 + j][lane] = ks;
        cur = nx;
    }

    // ---- value prefetch: wave's 4 rows (issued before barrier) ----
    const int vrow0 = wrow0 + h * 4;            // rows vrow0..vrow0+3
    const float4* vp = (const float4*)(value + (size_t)(base + vrow0) * 512);
    float4 vreg[8];
    #pragma unroll
    for (int j = 0; j < 4; ++j) {
        vreg[2*j]   = vp[j * 128 + lane];
        vreg[2*j+1] = vp[j * 128 + 64 + lane];
    }
    __syncthreads();                 // kslds complete (both halves)

    // ---- Phase A2: scores for the pair's 8 rows (both waves redundant) ----
    const int p  = (lane >> 3) & 3;   // qubit-pair 0..3
    const int jr = lane & 7;          // row-in-pair 0..7
    float4 k0 = *(const float4*)&kslds[0][wrow0 + jr][4 * p];
    float4 k1 = *(const float4*)&kslds[1][wrow0 + jr][4 * p];
    float4 bk4 = ((const float4*)bk)[p];
    float ax = k0.x + k1.x + bk4.x, az = k0.y + k1.y + bk4.y;
    float bx = k0.z + k1.z + bk4.z, bz = k0.w + k1.w + bk4.w;
    float cxa = 1.f, sxa = 0.f; if (ax > 0.f){ sxa = __sinf(0.5f*ax); cxa = __cosf(0.5f*ax); }
    float cpa = 1.f, spa = 0.f; if (az > 0.f){ spa = __sinf(0.5f*az); cpa = __cosf(0.5f*az); }
    float cxb = 1.f, sxb = 0.f; if (bx > 0.f){ sxb = __sinf(0.5f*bx); cxb = __cosf(0.5f*bx); }
    float cpb = 1.f, spb = 0.f; if (bz > 0.f){ spb = __sinf(0.5f*bz); cpb = __cosf(0.5f*bz); }
    C2 A00{cpa*cxa, -spa*cxa}, A01{-spa*sxa, -cpa*sxa};
    C2 A10{spa*sxa, -cpa*sxa}, A11{ cpa*cxa,  spa*cxa};
    C2 B00{cpb*cxb, -spb*cxb}, B01{-spb*sxb, -cpb*sxb};
    C2 B10{spb*sxb, -cpb*sxb}, B11{ cpb*cxb,  spb*cxb};
    C2 u = cadd(cmul(B00, cadd(A00, cscale(A01, c0))),
                cscale(cnegi(cmul(A01, B01)), s0));
    C2 v = cadd(cmul(B10, cadd(A10, cscale(A11, c0))),
                cscale(cnegi(cmul(A11, B11)), s0));
    float ps = u.x*u.x + u.y*u.y + v.x*v.x + v.y*v.y;
    ps += __shfl_xor(ps, 8);          // fold qubit-pairs (p bits at 3..4)
    ps += __shfl_xor(ps, 16);
    float w_all = __expf(ps * 0.125f); // lane holds w for row (lane&7)

    // pair w-sum (h==0 wave writes; fold over row bits 0..2)
    if (h == 0) {
        float sw = w_all;
        sw += __shfl_xor(sw, 1); sw += __shfl_xor(sw, 2); sw += __shfl_xor(sw, 4);
        if (lane == 0) wsums[pr] = sw;
    }

    // ---- Phase B: weighted sum of own 4 value rows (from registers) ----
    float4 aA = {0.f,0.f,0.f,0.f}, aB = {0.f,0.f,0.f,0.f};
    #pragma unroll
    for (int j = 0; j < 4; ++j) {
        float wj = __shfl(w_all, h * 4 + j);
        float4 v0 = vreg[2*j], v1 = vreg[2*j+1];
        aA.x = fmaf(wj, v0.x, aA.x); aA.y = fmaf(wj, v0.y, aA.y);
        aA.z = fmaf(wj, v0.z, aA.z); aA.w = fmaf(wj, v0.w, aA.w);
        aB.x = fmaf(wj, v1.x, aB.x); aB.y = fmaf(wj, v1.y, aB.y);
        aB.z = fmaf(wj, v1.z, aB.z); aB.w = fmaf(wj, v1.w, aB.w);
    }
    red[wv][lane] = aA;
    red[wv][64 + lane] = aB;
    __syncthreads();
    if (t < 128) {
        float4 q0 = red[0][t], q1 = red[1][t], q2 = red[2][t], q3 = red[3][t];
        float4 q4 = red[4][t], q5 = red[5][t], q6 = red[6][t], q7 = red[7][t];
        float4 o = { q0.x+q1.x+q2.x+q3.x+q4.x+q5.x+q6.x+q7.x,
                     q0.y+q1.y+q2.y+q3.y+q4.y+q5.y+q6.y+q7.y,
                     q0.z+q1.z+q2.z+q3.z+q4.z+q5.z+q6.z+q7.z,
                     q0.w+q1.w+q2.w+q3.w+q4.w+q5.w+q6.w+q7.w };
        ((float4*)partial)[((size_t)b * 64 + c) * 128 + t] = o;
    }
    if (t == 0)
        partialw[b * 64 + c] = wsums[0] + wsums[1] + wsums[2] + wsums[3];
}

// ---------------------------------------------------------------------------
// K2 k_mid: grid (dt 0..7, b 0..7), 512 threads. Block computes:
//   invS; cbuf = 64-chunk column sums; FULL ctx (redundant 8x per batch,
//   kills the cross-kernel ctx dependency); frow slice dt*64..+64 via 8-way
//   split-e + LDS reduce. Deep unroll (8 acc x unroll 8 -> ~64 loads in
//   flight) converts GEMV latency (round-5 k_tail: unroll4, 12 us/GEMV)
//   into pipelined streams. NO output broadcast here (that was 21 us at 64
//   blocks) - k_bcast does it at 512 blocks.
// ---------------------------------------------------------------------------
__global__ __launch_bounds__(512) void k_mid(const float* __restrict__ partial,
                                             const float* __restrict__ partialw,
                                             const float* __restrict__ Wv,
                                             const float* __restrict__ bv,
                                             const float* __restrict__ Wo,
                                             const float* __restrict__ bo,
                                             float* __restrict__ frow)
{
    const int dt = blockIdx.x;       // frow col-slice 0..7
    const int b  = blockIdx.y;       // batch 0..7
    const int t  = threadIdx.x;      // 0..511

    __shared__ float cbuf[512];
    __shared__ float xbuf[512];
    __shared__ float red[512];
    __shared__ float sS;

    // invS (wave 0)
    if (t < 64) {
        float s = partialw[b * 64 + t];
        s += __shfl_xor(s, 1);  s += __shfl_xor(s, 2);
        s += __shfl_xor(s, 4);  s += __shfl_xor(s, 8);
        s += __shfl_xor(s, 16); s += __shfl_xor(s, 32);
        if (t == 0) sS = 1.f / s;
    }

    // column sums over 64 chunks (coalesced; deep unroll for MLP)
    {
        float c0 = 0.f, c1 = 0.f, c2 = 0.f, c3 = 0.f;
        const float* pp = partial + (size_t)b * 32768 + t;
        #pragma unroll
        for (int cc = 0; cc < 64; cc += 4) {
            c0 += pp[(size_t)cc * 512];
            c1 += pp[(size_t)(cc + 1) * 512];
            c2 += pp[(size_t)(cc + 2) * 512];
            c3 += pp[(size_t)(cc + 3) * 512];
        }
        cbuf[t] = (c0 + c1) + (c2 + c3);
    }
    __syncthreads();                 // cbuf + sS visible
    const float invS = sS;

    // ctx[t] = invS * sum_e cbuf[e]*Wv[e][t] + bv[t]   (full, redundant)
    {
        float a0=0.f,a1=0.f,a2=0.f,a3=0.f,a4=0.f,a5=0.f,a6=0.f,a7=0.f;
        #pragma unroll 8
        for (int e = 0; e < 512; e += 8) {
            a0 = fmaf(cbuf[e],   Wv[(size_t)e * 512 + t],     a0);
            a1 = fmaf(cbuf[e+1], Wv[(size_t)(e+1) * 512 + t], a1);
            a2 = fmaf(cbuf[e+2], Wv[(size_t)(e+2) * 512 + t], a2);
            a3 = fmaf(cbuf[e+3], Wv[(size_t)(e+3) * 512 + t], a3);
            a4 = fmaf(cbuf[e+4], Wv[(size_t)(e+4) * 512 + t], a4);
            a5 = fmaf(cbuf[e+5], Wv[(size_t)(e+5) * 512 + t], a5);
            a6 = fmaf(cbuf[e+6], Wv[(size_t)(e+6) * 512 + t], a6);
            a7 = fmaf(cbuf[e+7], Wv[(size_t)(e+7) * 512 + t], a7);
        }
        xbuf[t] = (((a0+a1)+(a2+a3)) + ((a4+a5)+(a6+a7))) * invS + bv[t];
    }
    __syncthreads();                 // ctx visible

    // frow slice: thread (dl = t&63, g = t>>6) covers e in [g*64, g*64+64)
    {
        const int dl = t & 63, g = t >> 6;
        const int d  = dt * 64 + dl;
        const float* Wc = Wo + (size_t)(g * 64) * 512 + d;
        const float* xg = xbuf + g * 64;
        float a0=0.f,a1=0.f,a2=0.f,a3=0.f;
        #pragma unroll 8
        for (int e = 0; e < 64; e += 4) {
            a0 = fmaf(xg[e],   Wc[(size_t)e * 512],       a0);
            a1 = fmaf(xg[e+1], Wc[(size_t)(e+1) * 512],   a1);
            a2 = fmaf(xg[e+2], Wc[(size_t)(e+2) * 512],   a2);
            a3 = fmaf(xg[e+3], Wc[(size_t)(e+3) * 512],   a3);
        }
        red[t] = (a0 + a1) + (a2 + a3);
    }
    __syncthreads();
    if (t < 64) {
        float r = red[t]       + red[t + 64]  + red[t + 128] + red[t + 192]
                + red[t + 256] + red[t + 320] + red[t + 384] + red[t + 448];
        frow[b * 512 + dt * 64 + t] = r + bo[dt * 64 + t];
    }
}

// ---------------------------------------------------------------------------
// K3 k_bcast (round-3 verified, verbatim): grid (64,8), 256 threads. Block
// (s,b) writes rows b*2048+s*32 .. +31 with frow[b,:]. Pure float4 streaming
// stores at 512 blocks -> write-BW bound (~6 us).
// ---------------------------------------------------------------------------
__global__ __launch_bounds__(256) void k_bcast(const float* __restrict__ frow,
                                               float* __restrict__ out)
{
    int s = blockIdx.x, b = blockIdx.y, t = threadIdx.x;
    const int col4 = t & 127, h = t >> 7;
    float4 val = ((const float4*)frow)[b * 128 + col4];
    float4* o4 = (float4*)out
               + ((size_t)b * 2048 + s * 32 + h * 16) * 128 + col4;
    #pragma unroll
    for (int r = 0; r < 16; ++r) o4[(size_t)r * 128] = val;
}

extern "C" void kernel_launch(void* const* d_in, const int* in_sizes, int n_in,
                              void* d_out, int out_size, void* d_ws, size_t ws_size,
                              hipStream_t stream) {
    // setup_inputs order: query, key, value, Wq, bq, Wk, bk, Wv, bv, Wo, bo
    const float* key   = (const float*)d_in[1];
    const float* value = (const float*)d_in[2];
    const float* Wk    = (const float*)d_in[5];
    const float* bk    = (const float*)d_in[6];
    const float* Wv    = (const float*)d_in[7];
    const float* bv    = (const float*)d_in[8];
    const float* Wo    = (const float*)d_in[9];
    const float* bo    = (const float*)d_in[10];
    float* out = (float*)d_out;
    float* ws  = (float*)d_ws;

    // workspace layout (floats), ~1.05 MB
    float* partial  = ws;                 // 8*64*512 = 262144
    float* partialw = ws + 262144;        // 512
    float* frow     = ws + 262656;        // 4096

    k_score_wsum<<<dim3(64, 8), 512, 0, stream>>>(key, Wk, bk, value,
                                                  partial, partialw);
    k_mid       <<<dim3(8, 8),  512, 0, stream>>>(partial, partialw,
                                                  Wv, bv, Wo, bo, frow);
    k_bcast     <<<dim3(64, 8), 256, 0, stream>>>(frow, out);
}